// Round 1
// 393.974 us; speedup vs baseline: 1.0101x; 1.0101x over previous
//
#include <hip/hip_runtime.h>
#include <cstdint>

#define SIZE 1349
#define HALF 674
#define N2 (SIZE*SIZE)          // 1,819,801
#define LSIG 1000000
#define NB 8
#define GRID_RINGS 954          // rings 0..953 (corner r = 674*sqrt2 -> 953)
#define RANK_RINGS 600          // rings with ringOffset < LSIG are all < 600:
                                // offset(600) = #cells with x^2+y^2 <= 599*600 ~ pi*599.5^2 ~ 1.129M >= 1M
                                // even under worst-case Gauss-circle error (~2*pi*600 ~ 3.8K). Rings >= 600
                                // contain only rank >= LSIG cells -> gather zero-fills them analytically.
#define CAP 5376                // max ring cell count ~4350 (2*pi*674 + Gauss err)
#define MBUCKET 2048

// ================= exact integer sqrt =================
__device__ __forceinline__ int isqrt_i(int n) {
    int s = (int)sqrtf((float)n);
    while (s > 0 && s * s > n) s--;
    while ((s + 1) * (s + 1) <= n) s++;
    return s;
}

// Ring k row y: cells with x^2+y^2 in [k(k-1)+1, k(k+1)], |x|<=674.
// 0 = empty, 1 = single interval [-xhi,xhi], 2 = [-xhi,-xlo] u [xlo,xhi]
__device__ __forceinline__ int row_interval(int k, int y, int* xlo, int* xhi) {
    if (k == 0) { if (y == 0) { *xhi = 0; return 1; } return 0; }
    int yy = y * y;
    int B = k * (k + 1) - yy;
    if (B < 0) return 0;
    int h = isqrt_i(B);
    if (h > HALF) h = HALF;
    int A = k * (k - 1) + 1 - yy;
    *xhi = h;
    if (A <= 0) return 1;
    int f = isqrt_i(A);
    int lo = (f * f == A) ? f : f + 1;
    if (lo > h) return 0;
    *xlo = lo;
    return 2;
}

__device__ __forceinline__ uint32_t rowcnt(int k, int y) {
    int lo, hi;
    int kind = row_interval(k, y, &lo, &hi);
    if (kind == 0) return 0u;
    if (kind == 1) return (uint32_t)(2 * hi + 1);
    return (uint32_t)(2 * (hi - lo + 1));
}

// ================= pass 1: analytic per-ring counts (only rings < RANK_RINGS needed) =================
__global__ void k_prep1(uint32_t* __restrict__ ringCount) {
    __shared__ uint32_t red[256];
    int k = blockIdx.x, t = threadIdx.x;
    int ymaxv = min(k, HALF);
    int nrows = 2 * ymaxv + 1;
    uint32_t s = 0;
    for (int i = t; i < nrows; i += 256) s += rowcnt(k, i - ymaxv);
    red[t] = s;
    __syncthreads();
    for (int d = 128; d > 0; d >>= 1) { if (t < d) red[t] += red[t + d]; __syncthreads(); }
    if (t == 0) ringCount[k] = red[0];
}

// ================= pass 2: exclusive scan over ring counts + zero-region threshold =================
__global__ void k_prep2(const uint32_t* __restrict__ ringCount,
                        uint32_t* __restrict__ ringOffset,
                        uint32_t* __restrict__ nthresh) {
    __shared__ uint32_t s[1024];
    int t = threadIdx.x;
    uint32_t mine = (t < RANK_RINGS) ? ringCount[t] : 0u;
    s[t] = mine;
    __syncthreads();
    for (int d = 1; d < 1024; d <<= 1) {
        uint32_t x = (t >= d) ? s[t - d] : 0u;
        __syncthreads();
        s[t] += x;
        __syncthreads();
    }
    if (t < RANK_RINGS) ringOffset[t] = s[t] - mine;
    // First ring B with exclusive offset >= LSIG. excl[t] = s[t-1] (inclusive of t-1).
    // Cells are zero-filled iff x^2+y^2 >= B*(B-1)+1 (ring index monotone in radius^2).
    if (t >= 2 && t < RANK_RINGS && s[t - 1] >= LSIG && s[t - 2] < LSIG)
        *nthresh = (uint32_t)(t * (t - 1) + 1);
}

// ================= bucket map: monotone in f32 key bits =================
// p2 - tt is Sterbenz-exact (p2 in [tt-pi, tt+pi] subset [tt/2, 2tt] for k>=1),
// +PI and *SC are monotone f32 ops, trunc monotone => bucket order == key order.
__device__ __forceinline__ int bucket_of(uint32_t kb, float tt) {
    const float PI_F = 3.14159265358979323846f;
    const float SC = 325.94932f;  // MBUCKET / (2*pi)
    float p2 = __uint_as_float(kb);
    float u = (p2 - tt) + PI_F;   // ~[0, 2pi]
    int b = (int)(u * SC);
    return min(max(b, 0), MBUCKET - 1);
}

// ================= ring enumeration (identical in both phases) =================
// PHASE 0: histogram buckets. PHASE 1: scatter (key,idx) into bucket slots.
template<int PHASE>
__device__ __forceinline__ void enum_ring(int k, int ymaxv, float tt, int t,
                                          uint32_t* cnt, uint32_t* boff, uint64_t* T) {
#pragma clang fp contract(off)
    const float PI_F = 3.14159265358979323846f;
    int ntask = 2 * (ymaxv + 1);
    for (int task = t; task < ntask; task += 1024) {
        int y = task >> 1, side = task & 1;
        int xlo = 0, xhi = 0;
        int kind = row_interval(k, y, &xlo, &xhi);
        if (kind == 0) continue;
        int xs, xe;
        if (side == 0) {
            xs = -xhi; xe = (kind == 1) ? -1 : -xlo;
            if (xe < xs) continue;
        } else {
            xs = (kind == 1) ? 0 : xlo; xe = xhi;
        }
        for (int x = xs; x <= xe; ++x) {
            uint32_t kp, kn = 0;
            if (y == 0) {
                float phi = (x < 0) ? PI_F : 0.0f;   // acos(+-1)*sign(0)=0; +PI if x<0
                kp = __float_as_uint(tt + phi);
            } else {
                int nn = x * x + y * y;
                float rr = sqrtf((float)nn);          // exact int -> CR sqrt
                float q = (float)x / rr;              // CR f32 division
                float ac = (float)::acos((double)q);  // CR float acos (validated R1/R2)
                kp = __float_as_uint(tt + ac);
                kn = __float_as_uint(tt - ac);
            }
            uint32_t gx = (uint32_t)(x + HALF);
            uint32_t gp = (uint32_t)(y + HALF) * SIZE + gx;
            int bp = bucket_of(kp, tt);
            if (PHASE == 0) atomicAdd(&cnt[bp], 1u);
            else { uint32_t p = atomicAdd(&boff[bp], 1u); T[p] = ((uint64_t)kp << 32) | gp; }
            if (y > 0) {
                uint32_t gn = (uint32_t)(HALF - y) * SIZE + gx;
                int bn = bucket_of(kn, tt);
                if (PHASE == 0) atomicAdd(&cnt[bn], 1u);
                else { uint32_t p = atomicAdd(&boff[bn], 1u); T[p] = ((uint64_t)kn << 32) | gn; }
            }
        }
    }
}

// ================= pass 3: per-ring bucket-count ranking =================
// Only rings whose ranks the gather actually reads (offset < LSIG, i.e. k < ~566).
// Reversed block order: biggest surviving ring (k=565, ~3550 cells) starts first -> flat makespan.
__global__ __launch_bounds__(1024) void k_rank(const uint32_t* __restrict__ ringOffset,
                                               const uint32_t* __restrict__ ringCount,
                                               uint32_t* __restrict__ rank) {
#pragma clang fp contract(off)
    __shared__ uint64_t T[CAP];          // 43 KB
    __shared__ uint32_t cnt[MBUCKET];    // 8 KB
    __shared__ uint32_t boff[MBUCKET];   // 8 KB
    __shared__ uint32_t ps[1024];        // 4 KB  (total 63 KB -> 2 blocks/CU)
    const float PI_F = 3.14159265358979323846f;
    int k = (RANK_RINGS - 1) - blockIdx.x;
    int t = threadIdx.x;
    uint32_t off = ringOffset[k];
    if (off >= LSIG) return;             // ring entirely past the signal: gather zero-fills analytically
    if (k == 0) { if (t == 0) rank[HALF * SIZE + HALF] = 0u; return; }
    int ymaxv = min(k, HALF);
    int n = (int)ringCount[k];
    float tt = (2.0f * (float)k) * PI_F;  // same f32 roundings as ref

    cnt[2 * t] = 0u; cnt[2 * t + 1] = 0u;
    __syncthreads();

    enum_ring<0>(k, ymaxv, tt, t, cnt, boff, T);   // histogram
    __syncthreads();

    // exclusive scan of cnt[0..2048) via pair-sums + Hillis-Steele over 1024
    uint32_t c0 = cnt[2 * t], c1 = cnt[2 * t + 1];
    uint32_t s = c0 + c1;
    ps[t] = s;
    __syncthreads();
    for (int d = 1; d < 1024; d <<= 1) {
        uint32_t x = (t >= d) ? ps[t - d] : 0u;
        __syncthreads();
        ps[t] += x;
        __syncthreads();
    }
    uint32_t excl = ps[t] - s;
    boff[2 * t] = excl;
    boff[2 * t + 1] = excl + c0;
    __syncthreads();

    enum_ring<1>(k, ymaxv, tt, t, cnt, boff, T);   // scatter; boff[b] -> bucket end
    __syncthreads();

    // rank = ringOff + bucketStart + (# bucket members with smaller (key,idx))
    for (int i = t; i < n; i += 1024) {
        uint64_t v = T[i];
        uint32_t kb = (uint32_t)(v >> 32);
        int b = bucket_of(kb, tt);
        uint32_t end = boff[b];
        uint32_t start = end - cnt[b];
        uint32_t c = 0;
        for (uint32_t j = start; j < end; ++j) c += (T[j] < v) ? 1u : 0u;
        rank[(uint32_t)v] = off + start + c;
    }
}

// ================= pass 4: tiled gather (32x8 cells per 256-thread block) =================
// Vertically adjacent grid cells are rank-adjacent (circle neighbors), so an 8-row tile
// gives each wave 2 rows x 32 cols -> input-read cache lines are shared across rows
// instead of one line per lane. Writes stay >=512B contiguous per row segment.
typedef float vfloat4 __attribute__((ext_vector_type(4)));

#define TW 32
#define TH 8

__global__ __launch_bounds__(256) void k_gather(const vfloat4* __restrict__ in,
                                                const uint32_t* __restrict__ rank,
                                                const uint32_t* __restrict__ nthresh,
                                                vfloat4* __restrict__ out) {
    int tx = threadIdx.x & (TW - 1);
    int ty = threadIdx.x >> 5;
    int col = blockIdx.x * TW + tx;
    int row = blockIdx.y * TH + ty;
    if (col >= SIZE || row >= SIZE) return;
    int g = row * SIZE + col;
    int dx = col - HALF, dy = row - HALF;
    uint32_t n = (uint32_t)(dx * dx + dy * dy);
    uint32_t q = 0xFFFFFFFFu;
    if (n < *nthresh) q = rank[g];     // outside threshold: ring offset >= LSIG, rank never written
    if (q < LSIG) {
#pragma unroll
        for (int b = 0; b < NB; ++b) {
            vfloat4 v = in[b * LSIG + (int)q];
            __builtin_nontemporal_store(v, &out[b * N2 + g]);
        }
    } else {
        vfloat4 z = {0.f, 0.f, 0.f, 0.f};
#pragma unroll
        for (int b = 0; b < NB; ++b)
            __builtin_nontemporal_store(z, &out[b * N2 + g]);
    }
}

extern "C" void kernel_launch(void* const* d_in, const int* in_sizes, int n_in,
                              void* d_out, int out_size, void* d_ws, size_t ws_size,
                              hipStream_t stream) {
    const float* in = (const float*)d_in[0];
    float* out = (float*)d_out;
    uint8_t* ws = (uint8_t*)d_ws;

    constexpr size_t RANK_OFF   = 0;                  // N2*4 = 7,279,204 -> pad
    constexpr size_t COUNT_OFF  = 7279616;            // RANK_RINGS*4
    constexpr size_t OFFSET_OFF = COUNT_OFF + 4096;   // RANK_RINGS*4
    constexpr size_t THRESH_OFF = OFFSET_OFF + 4096;  // 4

    uint32_t* rank       = (uint32_t*)(ws + RANK_OFF);
    uint32_t* ringCount  = (uint32_t*)(ws + COUNT_OFF);
    uint32_t* ringOffset = (uint32_t*)(ws + OFFSET_OFF);
    uint32_t* nthresh    = (uint32_t*)(ws + THRESH_OFF);

    k_prep1<<<RANK_RINGS, 256, 0, stream>>>(ringCount);
    k_prep2<<<1, 1024, 0, stream>>>(ringCount, ringOffset, nthresh);
    k_rank<<<RANK_RINGS, 1024, 0, stream>>>(ringOffset, ringCount, rank);

    dim3 gb((SIZE + TW - 1) / TW, (SIZE + TH - 1) / TH);
    k_gather<<<gb, 256, 0, stream>>>((const vfloat4*)in, rank, nthresh, (vfloat4*)out);
}

// Round 2
// 371.705 us; speedup vs baseline: 1.0706x; 1.0599x over previous
//
#include <hip/hip_runtime.h>
#include <cstdint>

#define SIZE 1349
#define HALF 674
#define N2 (SIZE*SIZE)          // 1,819,801
#define LSIG 1000000
#define NB 8
#define GRID_RINGS 954          // rings 0..953 (corner r = 674*sqrt2 -> 953)
#define RANK_RINGS 600          // rings with ringOffset < LSIG are all < 600 (see round-1 note)
#define CAP 5376                // max ring cell count ~4350 (2*pi*674 + Gauss err)
#define MBUCKET 2048

// ================= exact integer sqrt =================
__device__ __forceinline__ int isqrt_i(int n) {
    int s = (int)sqrtf((float)n);
    while (s > 0 && s * s > n) s--;
    while ((s + 1) * (s + 1) <= n) s++;
    return s;
}

// Ring k row y: cells with x^2+y^2 in [k(k-1)+1, k(k+1)], |x|<=674.
// 0 = empty, 1 = single interval [-xhi,xhi], 2 = [-xhi,-xlo] u [xlo,xhi]
__device__ __forceinline__ int row_interval(int k, int y, int* xlo, int* xhi) {
    if (k == 0) { if (y == 0) { *xhi = 0; return 1; } return 0; }
    int yy = y * y;
    int B = k * (k + 1) - yy;
    if (B < 0) return 0;
    int h = isqrt_i(B);
    if (h > HALF) h = HALF;
    int A = k * (k - 1) + 1 - yy;
    *xhi = h;
    if (A <= 0) return 1;
    int f = isqrt_i(A);
    int lo = (f * f == A) ? f : f + 1;
    if (lo > h) return 0;
    *xlo = lo;
    return 2;
}

__device__ __forceinline__ uint32_t rowcnt(int k, int y) {
    int lo, hi;
    int kind = row_interval(k, y, &lo, &hi);
    if (kind == 0) return 0u;
    if (kind == 1) return (uint32_t)(2 * hi + 1);
    return (uint32_t)(2 * (hi - lo + 1));
}

// ================= pass 1: analytic per-ring counts =================
__global__ void k_prep1(uint32_t* __restrict__ ringCount) {
    __shared__ uint32_t red[256];
    int k = blockIdx.x, t = threadIdx.x;
    int ymaxv = min(k, HALF);
    int nrows = 2 * ymaxv + 1;
    uint32_t s = 0;
    for (int i = t; i < nrows; i += 256) s += rowcnt(k, i - ymaxv);
    red[t] = s;
    __syncthreads();
    for (int d = 128; d > 0; d >>= 1) { if (t < d) red[t] += red[t + d]; __syncthreads(); }
    if (t == 0) ringCount[k] = red[0];
}

// ================= pass 2: exclusive scan over ring counts + zero-region threshold =================
__global__ void k_prep2(const uint32_t* __restrict__ ringCount,
                        uint32_t* __restrict__ ringOffset,
                        uint32_t* __restrict__ nthresh) {
    __shared__ uint32_t s[1024];
    int t = threadIdx.x;
    uint32_t mine = (t < RANK_RINGS) ? ringCount[t] : 0u;
    s[t] = mine;
    __syncthreads();
    for (int d = 1; d < 1024; d <<= 1) {
        uint32_t x = (t >= d) ? s[t - d] : 0u;
        __syncthreads();
        s[t] += x;
        __syncthreads();
    }
    if (t < RANK_RINGS) ringOffset[t] = s[t] - mine;
    // First ring B with exclusive offset >= LSIG: cells zero iff x^2+y^2 >= B*(B-1)+1.
    if (t >= 2 && t < RANK_RINGS && s[t - 1] >= LSIG && s[t - 2] < LSIG)
        *nthresh = (uint32_t)(t * (t - 1) + 1);
}

// ================= bucket map: monotone in f32 key bits =================
__device__ __forceinline__ int bucket_of(uint32_t kb, float tt) {
    const float PI_F = 3.14159265358979323846f;
    const float SC = 325.94932f;  // MBUCKET / (2*pi)
    float p2 = __uint_as_float(kb);
    float u = (p2 - tt) + PI_F;   // ~[0, 2pi]
    int b = (int)(u * SC);
    return min(max(b, 0), MBUCKET - 1);
}

// ================= ring enumeration (identical in both phases) =================
template<int PHASE>
__device__ __forceinline__ void enum_ring(int k, int ymaxv, float tt, int t,
                                          uint32_t* cnt, uint32_t* boff, uint64_t* T) {
#pragma clang fp contract(off)
    const float PI_F = 3.14159265358979323846f;
    int ntask = 2 * (ymaxv + 1);
    for (int task = t; task < ntask; task += 1024) {
        int y = task >> 1, side = task & 1;
        int xlo = 0, xhi = 0;
        int kind = row_interval(k, y, &xlo, &xhi);
        if (kind == 0) continue;
        int xs, xe;
        if (side == 0) {
            xs = -xhi; xe = (kind == 1) ? -1 : -xlo;
            if (xe < xs) continue;
        } else {
            xs = (kind == 1) ? 0 : xlo; xe = xhi;
        }
        for (int x = xs; x <= xe; ++x) {
            uint32_t kp, kn = 0;
            if (y == 0) {
                float phi = (x < 0) ? PI_F : 0.0f;
                kp = __float_as_uint(tt + phi);
            } else {
                int nn = x * x + y * y;
                float rr = sqrtf((float)nn);          // exact int -> CR sqrt
                float q = (float)x / rr;              // CR f32 division
                float ac = (float)::acos((double)q);  // CR float acos (validated R1/R2)
                kp = __float_as_uint(tt + ac);
                kn = __float_as_uint(tt - ac);
            }
            uint32_t gx = (uint32_t)(x + HALF);
            uint32_t gp = (uint32_t)(y + HALF) * SIZE + gx;
            int bp = bucket_of(kp, tt);
            if (PHASE == 0) atomicAdd(&cnt[bp], 1u);
            else { uint32_t p = atomicAdd(&boff[bp], 1u); T[p] = ((uint64_t)kp << 32) | gp; }
            if (y > 0) {
                uint32_t gn = (uint32_t)(HALF - y) * SIZE + gx;
                int bn = bucket_of(kn, tt);
                if (PHASE == 0) atomicAdd(&cnt[bn], 1u);
                else { uint32_t p = atomicAdd(&boff[bn], 1u); T[p] = ((uint64_t)kn << 32) | gn; }
            }
        }
    }
}

// ================= pass 3: per-ring bucket-count ranking (rings with offset < LSIG) =================
__global__ __launch_bounds__(1024) void k_rank(const uint32_t* __restrict__ ringOffset,
                                               const uint32_t* __restrict__ ringCount,
                                               uint32_t* __restrict__ rank) {
#pragma clang fp contract(off)
    __shared__ uint64_t T[CAP];          // 43 KB
    __shared__ uint32_t cnt[MBUCKET];    // 8 KB
    __shared__ uint32_t boff[MBUCKET];   // 8 KB
    __shared__ uint32_t ps[1024];        // 4 KB  (total 63 KB -> 2 blocks/CU)
    const float PI_F = 3.14159265358979323846f;
    int k = (RANK_RINGS - 1) - blockIdx.x;
    int t = threadIdx.x;
    uint32_t off = ringOffset[k];
    if (off >= LSIG) return;             // ring entirely past the signal
    if (k == 0) { if (t == 0) rank[HALF * SIZE + HALF] = 0u; return; }
    int ymaxv = min(k, HALF);
    int n = (int)ringCount[k];
    float tt = (2.0f * (float)k) * PI_F;

    cnt[2 * t] = 0u; cnt[2 * t + 1] = 0u;
    __syncthreads();

    enum_ring<0>(k, ymaxv, tt, t, cnt, boff, T);   // histogram
    __syncthreads();

    uint32_t c0 = cnt[2 * t], c1 = cnt[2 * t + 1];
    uint32_t s = c0 + c1;
    ps[t] = s;
    __syncthreads();
    for (int d = 1; d < 1024; d <<= 1) {
        uint32_t x = (t >= d) ? ps[t - d] : 0u;
        __syncthreads();
        ps[t] += x;
        __syncthreads();
    }
    uint32_t excl = ps[t] - s;
    boff[2 * t] = excl;
    boff[2 * t + 1] = excl + c0;
    __syncthreads();

    enum_ring<1>(k, ymaxv, tt, t, cnt, boff, T);   // scatter; boff[b] -> bucket end
    __syncthreads();

    for (int i = t; i < n; i += 1024) {
        uint64_t v = T[i];
        uint32_t kb = (uint32_t)(v >> 32);
        int b = bucket_of(kb, tt);
        uint32_t end = boff[b];
        uint32_t start = end - cnt[b];
        uint32_t c = 0;
        for (uint32_t j = start; j < end; ++j) c += (T[j] < v) ? 1u : 0u;
        rank[(uint32_t)v] = off + start + c;
    }
}

// ================= pass 4: gather, one batch per blockIdx.z =================
// 32x8 tile per block. With the batch on z, a wave's working set is one batch only:
// ~32 input lines (4 KB) with 8-row vertical reuse -> L1-resident; 2 memory streams
// per wave instead of 16. rank[] is re-read per z (8x4 MB streaming, L2-shared
// across the 8 z-blocks of a tile).
typedef float vfloat4 __attribute__((ext_vector_type(4)));

#define TW 32
#define TH 8

__global__ __launch_bounds__(256) void k_gather(const vfloat4* __restrict__ in,
                                                const uint32_t* __restrict__ rank,
                                                const uint32_t* __restrict__ nthresh,
                                                vfloat4* __restrict__ out) {
    int tx = threadIdx.x & (TW - 1);
    int ty = threadIdx.x >> 5;
    int col = blockIdx.x * TW + tx;
    int row = blockIdx.y * TH + ty;
    int b = blockIdx.z;
    if (col >= SIZE || row >= SIZE) return;
    int g = row * SIZE + col;
    int dx = col - HALF, dy = row - HALF;
    uint32_t n = (uint32_t)(dx * dx + dy * dy);
    uint32_t q = 0xFFFFFFFFu;
    if (n < *nthresh) q = rank[g];     // outside threshold: rank never written (poison-safe)
    if (q < LSIG) {
        vfloat4 v = in[b * LSIG + (int)q];
        __builtin_nontemporal_store(v, &out[b * N2 + g]);
    } else {
        vfloat4 z = {0.f, 0.f, 0.f, 0.f};
        __builtin_nontemporal_store(z, &out[b * N2 + g]);
    }
}

extern "C" void kernel_launch(void* const* d_in, const int* in_sizes, int n_in,
                              void* d_out, int out_size, void* d_ws, size_t ws_size,
                              hipStream_t stream) {
    const float* in = (const float*)d_in[0];
    float* out = (float*)d_out;
    uint8_t* ws = (uint8_t*)d_ws;

    constexpr size_t RANK_OFF   = 0;                  // N2*4 = 7,279,204 -> pad
    constexpr size_t COUNT_OFF  = 7279616;            // RANK_RINGS*4
    constexpr size_t OFFSET_OFF = COUNT_OFF + 4096;   // RANK_RINGS*4
    constexpr size_t THRESH_OFF = OFFSET_OFF + 4096;  // 4

    uint32_t* rank       = (uint32_t*)(ws + RANK_OFF);
    uint32_t* ringCount  = (uint32_t*)(ws + COUNT_OFF);
    uint32_t* ringOffset = (uint32_t*)(ws + OFFSET_OFF);
    uint32_t* nthresh    = (uint32_t*)(ws + THRESH_OFF);

    k_prep1<<<RANK_RINGS, 256, 0, stream>>>(ringCount);
    k_prep2<<<1, 1024, 0, stream>>>(ringCount, ringOffset, nthresh);
    k_rank<<<RANK_RINGS, 1024, 0, stream>>>(ringOffset, ringCount, rank);

    dim3 gb((SIZE + TW - 1) / TW, (SIZE + TH - 1) / TH, NB);
    k_gather<<<gb, 256, 0, stream>>>((const vfloat4*)in, rank, nthresh, (vfloat4*)out);
}